// Round 13
// baseline (144.474 us; speedup 1.0000x reference)
//
#include <hip/hip_runtime.h>

#define F 128
#define BIN_CAP 6144   // edges per 256-row bin: mean 3061, sigma ~55 -> 56-sigma margin

typedef _Float16 half8 __attribute__((ext_vector_type(8)));
typedef float f32x4 __attribute__((ext_vector_type(4)));

// ---------- f16 helpers ----------
__device__ inline unsigned int f2_to_h2(float a, float b) {
    union { _Float16 h[2]; unsigned int u; } c;
    c.h[0] = (_Float16)a; c.h[1] = (_Float16)b;
    return c.u;
}
__device__ inline float2 h2_to_f2(unsigned int v) {
    union { unsigned int u; _Float16 h[2]; } c; c.u = v;
    return make_float2((float)c.h[0], (float)c.h[1]);
}

// ---------- row-oriented convert: xf rows + alpha1 (wave/node); tail blocks: W1/W2/binCnt ----------
// tail index space (45 blocks x 256): [0,256) binCnt=0 ; [256,256+8192) w1f ; [8448,11520) w2f
__global__ __launch_bounds__(256) void convert_kernel(
    const float* __restrict__ x, const float* __restrict__ aw1, const float* __restrict__ ab1,
    const float* __restrict__ W1, const float* __restrict__ W2,
    unsigned int* __restrict__ xf, float* __restrict__ alpha1,
    unsigned int* __restrict__ w1f, unsigned int* __restrict__ w2f,
    int* __restrict__ binCnt, int n, int nodeBlocks) {
    if (blockIdx.x >= nodeBlocks) {
        int i = (blockIdx.x - nodeBlocks) * 256 + threadIdx.x;  // 0..11519
        if (i < 256) {
            binCnt[i] = 0;
        } else if (i < 256 + F * F / 2) {
            int j = i - 256;
            float2 v = ((const float2*)W1)[j];
            w1f[j] = f2_to_h2(v.x, v.y);
        } else {
            int j = i - 256 - F * F / 2;   // [0, 3072)
            int m = j >> 6;
            if (m < 40) {
                float2 v = ((const float2*)W2)[j];
                w2f[j] = f2_to_h2(v.x, v.y);
            } else {
                w2f[j] = 0u;
            }
        }
        return;
    }
    int wid = blockIdx.x * 4 + (threadIdx.x >> 6);
    int lane = threadIdx.x & 63;
    if (wid >= n) return;
    float2 xv = ((const float2*)(x + (size_t)wid * F))[lane];
    float2 awv = ((const float2*)aw1)[lane];
    float s = xv.x * awv.x + xv.y * awv.y;
    #pragma unroll
    for (int off = 32; off > 0; off >>= 1) s += __shfl_down(s, off);
    if (lane == 0) alpha1[wid] = 1.0f / (1.0f + expf(-(s + ab1[0])));
    xf[(size_t)wid * 64 + lane] = f2_to_h2(xv.x, xv.y);
}

// ---------- CSR build via LDS multisplit ----------
__global__ __launch_bounds__(256) void binning_kernel(const int* __restrict__ row,
                                                      const int* __restrict__ col,
                                                      int* __restrict__ binCnt,
                                                      unsigned int* __restrict__ binned, int e) {
    __shared__ int cnt1[256], base[256], cnt2[256];
    int chunk0 = blockIdx.x * 4096;
    cnt1[threadIdx.x] = 0;
    cnt2[threadIdx.x] = 0;
    __syncthreads();
    #pragma unroll
    for (int k = 0; k < 16; ++k) {
        int i = chunk0 + k * 256 + threadIdx.x;
        if (i < e) atomicAdd(&cnt1[row[i] >> 8], 1);
    }
    __syncthreads();
    int c = cnt1[threadIdx.x];
    if (c > 0) base[threadIdx.x] = atomicAdd(&binCnt[threadIdx.x], c);
    __syncthreads();
    #pragma unroll
    for (int k = 0; k < 16; ++k) {
        int i = chunk0 + k * 256 + threadIdx.x;
        if (i < e) {
            int r = row[i], cl = col[i];
            int b = r >> 8;
            int rk = atomicAdd(&cnt2[b], 1);
            int pos = base[b] + rk;
            if (pos < BIN_CAP)  // guard (never triggers at 56 sigma)
                binned[(size_t)b * BIN_CAP + pos] = ((unsigned int)(r & 255) << 24) | (unsigned int)cl;
        }
    }
}

// One block per bin: scan binCnt, LDS-hist 256 rows, write rowStart/dinv/csr_col
__global__ __launch_bounds__(256) void finalize_kernel(const int* __restrict__ binCnt,
                                                       const unsigned int* __restrict__ binned,
                                                       int* __restrict__ rowStart,
                                                       float* __restrict__ dinv,
                                                       int* __restrict__ csr_col,
                                                       int n, int nb) {
    __shared__ int tmp[256], lc[256], lo[256], lc2[256];
    __shared__ int sBase, sSz;
    int tid = threadIdx.x;
    int b = blockIdx.x;
    int v = (tid < nb) ? binCnt[tid] : 0;
    tmp[tid] = v;
    __syncthreads();
    #pragma unroll
    for (int off = 1; off < 256; off <<= 1) {
        int t = (tid >= off) ? tmp[tid - off] : 0;
        __syncthreads();
        tmp[tid] += t;
        __syncthreads();
    }
    if (tid == b) { sBase = tmp[b] - v; sSz = v; }
    lc[tid] = 0;
    lc2[tid] = 0;
    __syncthreads();
    int base = sBase, sz = sSz;
    for (int i = tid; i < sz; i += 256) {
        unsigned int pv = binned[(size_t)b * BIN_CAP + i];
        atomicAdd(&lc[pv >> 24], 1);
    }
    __syncthreads();
    int cv = lc[tid];
    tmp[tid] = cv;
    __syncthreads();
    #pragma unroll
    for (int off = 1; off < 256; off <<= 1) {
        int t = (tid >= off) ? tmp[tid - off] : 0;
        __syncthreads();
        tmp[tid] += t;
        __syncthreads();
    }
    int myLo = tmp[tid] - cv;
    lo[tid] = myLo;
    int rowId = (b << 8) + tid;
    if (rowId < n) {
        rowStart[rowId] = base + myLo;
        dinv[rowId] = rsqrtf((float)(cv + 1));   // +1 self loop
    }
    if (tid == 0 && b == nb - 1) rowStart[n] = base + sz;
    __syncthreads();
    for (int i = tid; i < sz; i += 256) {
        unsigned int pv = binned[(size_t)b * BIN_CAP + i];
        int rl = pv >> 24;
        int rk = atomicAdd(&lc2[rl], 1);
        csr_col[base + lo[rl] + rk] = (int)(pv & 0xFFFFFFu);
    }
}

// ---------- gather pass over one 64-feature half (working set 6.4MB -> better L2 hit) ----------
// 32-lane group per node: ui = lane&31 covers the half-row's 32 uints (128B, one coalesced read/edge)
__global__ __launch_bounds__(256) void gather_half_kernel(
    const unsigned int* __restrict__ xf, const int* __restrict__ rowStart,
    const int* __restrict__ csr_col, const float* __restrict__ dinv,
    const float* __restrict__ alpha1, unsigned int* __restrict__ zf, int n, int half) {
    int grp = (blockIdx.x * 256 + threadIdx.x) >> 5;   // node
    int ui = threadIdx.x & 31;
    if (grp >= n) return;
    size_t rowBase = (size_t)grp * 64 + half * 32;
    float2 xv = h2_to_f2(xf[rowBase + ui]);
    float dr = dinv[grp];
    float2 acc;
    acc.x = dr * dr * xv.x;
    acc.y = dr * dr * xv.y;
    int j = rowStart[grp], en = rowStart[grp + 1];
    for (; j + 3 < en; j += 4) {
        int c0 = csr_col[j], c1 = csr_col[j + 1], c2 = csr_col[j + 2], c3 = csr_col[j + 3];
        float w0 = dr * dinv[c0], w1 = dr * dinv[c1], w2 = dr * dinv[c2], w3 = dr * dinv[c3];
        float2 f0 = h2_to_f2(xf[(size_t)c0 * 64 + half * 32 + ui]);
        float2 f1 = h2_to_f2(xf[(size_t)c1 * 64 + half * 32 + ui]);
        float2 f2 = h2_to_f2(xf[(size_t)c2 * 64 + half * 32 + ui]);
        float2 f3 = h2_to_f2(xf[(size_t)c3 * 64 + half * 32 + ui]);
        acc.x += w0 * f0.x; acc.y += w0 * f0.y;
        acc.x += w1 * f1.x; acc.y += w1 * f1.y;
        acc.x += w2 * f2.x; acc.y += w2 * f2.y;
        acc.x += w3 * f3.x; acc.y += w3 * f3.y;
    }
    for (; j < en; ++j) {
        int c0 = csr_col[j];
        float w0 = dr * dinv[c0];
        float2 f0 = h2_to_f2(xf[(size_t)c0 * 64 + half * 32 + ui]);
        acc.x += w0 * f0.x; acc.y += w0 * f0.y;
    }
    float a = alpha1[grp];
    float ca = 1.0f - a, cb = 2.0f * a - 1.0f;
    zf[rowBase + ui] = f2_to_h2(ca * xv.x + cb * acc.x, ca * xv.y + cb * acc.y);
}

// ---------- fused dense: h = relu(z@W1^T + b1), alpha2 = sigmoid(h.aw2+ab2), yf = h@W2^T ----------
// 64 nodes/block, 4 waves; wave w owns rows 16w..16w+15.
// MFMA 16x16x32 f16: A lane(l): row=l&15, k=ks*32+(l>>4)*8+j ; B lane(l): col=l&15, same k
// D lane(l): col=l&15, row=(l>>4)*4+r
__global__ __launch_bounds__(256) void mfma_dense_kernel(
    const _Float16* __restrict__ zf, const _Float16* __restrict__ w1f,
    const float* __restrict__ b1, const float* __restrict__ aw2,
    const float* __restrict__ ab2, const _Float16* __restrict__ w2f,
    _Float16* __restrict__ yf, float* __restrict__ alpha2, int n) {
    __shared__ _Float16 hs[64 * F];   // XOR-swizzled: byte ^= (row&7)<<4
    int wv = threadIdx.x >> 6;
    int l = threadIdx.x & 63;
    int lr = l & 15;
    int kg = l >> 4;
    int node0 = blockIdx.x * 64;

    int arow = node0 + wv * 16 + lr;
    bool rowok = arow < n;
    half8 afr[4];
    half8 hzero = {0, 0, 0, 0, 0, 0, 0, 0};
    #pragma unroll
    for (int ks = 0; ks < 4; ++ks) {
        afr[ks] = rowok ? *(const half8*)(zf + (size_t)arow * F + ks * 32 + kg * 8) : hzero;
    }

    f32x4 acc[8];
    #pragma unroll
    for (int ct = 0; ct < 8; ++ct) {
        f32x4 a = {0.f, 0.f, 0.f, 0.f};
        #pragma unroll
        for (int ks = 0; ks < 4; ++ks) {
            half8 b = *(const half8*)(w1f + (size_t)(ct * 16 + lr) * F + ks * 32 + kg * 8);
            a = __builtin_amdgcn_mfma_f32_16x16x32_f16(afr[ks], b, a, 0, 0, 0);
        }
        acc[ct] = a;
    }

    float part[4] = {0.f, 0.f, 0.f, 0.f};
    #pragma unroll
    for (int ct = 0; ct < 8; ++ct) {
        int colc = ct * 16 + lr;
        float bv = b1[colc];
        float av = aw2[colc];
        #pragma unroll
        for (int r = 0; r < 4; ++r) {
            float h = fmaxf(acc[ct][r] + bv, 0.f);
            part[r] += h * av;
            int hrow = wv * 16 + kg * 4 + r;
            int byteoff = (hrow * 256 + colc * 2) ^ ((hrow & 7) << 4);
            *(_Float16*)((char*)hs + byteoff) = (_Float16)h;
        }
    }
    #pragma unroll
    for (int off = 1; off < 16; off <<= 1) {
        #pragma unroll
        for (int r = 0; r < 4; ++r) part[r] += __shfl_xor(part[r], off);
    }
    if (lr == 0) {
        #pragma unroll
        for (int r = 0; r < 4; ++r) {
            int nd = node0 + wv * 16 + kg * 4 + r;
            if (nd < n) alpha2[nd] = 1.0f / (1.0f + expf(-(part[r] + ab2[0])));
        }
    }
    __syncthreads();

    int hrow = wv * 16 + lr;
    half8 a2[4];
    #pragma unroll
    for (int ks = 0; ks < 4; ++ks) {
        int byteoff = (hrow * 256 + (ks * 32 + kg * 8) * 2) ^ ((hrow & 7) << 4);
        a2[ks] = *(const half8*)((char*)hs + byteoff);
    }
    #pragma unroll
    for (int ct = 0; ct < 3; ++ct) {
        f32x4 a = {0.f, 0.f, 0.f, 0.f};
        #pragma unroll
        for (int ks = 0; ks < 4; ++ks) {
            half8 b = *(const half8*)(w2f + (size_t)(ct * 16 + lr) * F + ks * 32 + kg * 8);
            a = __builtin_amdgcn_mfma_f32_16x16x32_f16(a2[ks], b, a, 0, 0, 0);
        }
        int colc = ct * 16 + lr;
        if (colc < 40) {
            #pragma unroll
            for (int r = 0; r < 4; ++r) {
                int nd = node0 + wv * 16 + kg * 4 + r;
                if (nd < n) yf[(size_t)nd * 40 + colc] = (_Float16)a[r];
            }
        }
    }
}

// ---------- gather on 40-dim projected features + mix + bias (final output) ----------
__global__ void gather40_kernel(const _Float16* __restrict__ yf,
                                const int* __restrict__ rowStart, const int* __restrict__ csr_col,
                                const float* __restrict__ dinv, const float* __restrict__ alpha,
                                const float* __restrict__ bias, float* __restrict__ out, int n) {
    int node = blockIdx.x * 8 + threadIdx.x / 40;
    int lane = threadIdx.x % 40;
    if (node >= n) return;
    float yv = (float)yf[(size_t)node * 40 + lane];
    float dr = dinv[node];
    float acc = dr * dr * yv;
    int j = rowStart[node], en = rowStart[node + 1];
    for (; j + 3 < en; j += 4) {
        int c0 = csr_col[j], c1 = csr_col[j + 1], c2 = csr_col[j + 2], c3 = csr_col[j + 3];
        acc += dr * dinv[c0] * (float)yf[(size_t)c0 * 40 + lane];
        acc += dr * dinv[c1] * (float)yf[(size_t)c1 * 40 + lane];
        acc += dr * dinv[c2] * (float)yf[(size_t)c2 * 40 + lane];
        acc += dr * dinv[c3] * (float)yf[(size_t)c3 * 40 + lane];
    }
    for (; j < en; ++j) {
        int c0 = csr_col[j];
        acc += dr * dinv[c0] * (float)yf[(size_t)c0 * 40 + lane];
    }
    float a = alpha[node];
    out[(size_t)node * 40 + lane] = (1.0f - a) * yv + (2.0f * a - 1.0f) * acc + bias[lane];
}

extern "C" void kernel_launch(void* const* d_in, const int* in_sizes, int n_in,
                              void* d_out, int out_size, void* d_ws, size_t ws_size,
                              hipStream_t stream) {
    const float* x   = (const float*)d_in[0];
    const int*   ei  = (const int*)d_in[1];
    const float* aw1 = (const float*)d_in[2];
    const float* ab1 = (const float*)d_in[3];
    const float* W1  = (const float*)d_in[4];
    const float* b1  = (const float*)d_in[5];
    const float* aw2 = (const float*)d_in[6];
    const float* ab2 = (const float*)d_in[7];
    const float* W2  = (const float*)d_in[8];
    const float* b2  = (const float*)d_in[9];
    float* out = (float*)d_out;

    int n = in_sizes[0] / F;   // 50000
    int e = in_sizes[1] / 2;   // 600000
    const int* row = ei;
    const int* col = ei + e;
    int nb = (n + 255) >> 8;   // 196 bins of 256 rows

    // workspace layout, all regions 16B-aligned
    char* p = (char*)d_ws;
    auto alloc = [&](size_t bytes) { char* q = p; p += (bytes + 15) & ~(size_t)15; return q; };
    int*   binCnt   = (int*)alloc(256 * 4);
    int*   rowStart = (int*)alloc((size_t)(n + 2) * 4);
    float* dinv     = (float*)alloc((size_t)n * 4);
    float* alpha1   = (float*)alloc((size_t)n * 4);
    unsigned int* binned = (unsigned int*)alloc((size_t)nb * BIN_CAP * 4);
    int*   csr_col  = (int*)alloc((size_t)e * 4);
    unsigned int* w1f = (unsigned int*)alloc((size_t)F * F * 2);
    unsigned int* w2f = (unsigned int*)alloc((size_t)48 * F * 2);
    unsigned int* xf  = (unsigned int*)alloc((size_t)n * 64 * 4);
    unsigned int* zf  = (unsigned int*)alloc((size_t)n * 64 * 4);
    _Float16* yfbuf = (_Float16*)alloc((size_t)n * 40 * 2);
    float* alpha2   = (float*)alloc((size_t)n * 4);

    // ---- convert (xf rows + alpha1; tail: W1/W2/binCnt) ----
    int nodeBlocks = (n + 3) / 4;                       // 12500
    int tailBlocks = (256 + F * F / 2 + 48 * F / 2 + 255) / 256;  // 45
    convert_kernel<<<nodeBlocks + tailBlocks, 256, 0, stream>>>(
        x, aw1, ab1, W1, W2, xf, alpha1, w1f, w2f, binCnt, n, nodeBlocks);

    // ---- CSR build: multisplit binning + per-bin finalize ----
    binning_kernel<<<(e + 4095) / 4096, 256, 0, stream>>>(row, col, binCnt, binned, e);
    finalize_kernel<<<nb, 256, 0, stream>>>(binCnt, binned, rowStart, dinv, csr_col, n, nb);

    // ---- layer 1 gather -> z (f16), two half-feature passes for L2 locality ----
    int gHalfBlk = (n * 32 + 255) / 256;   // 6250
    gather_half_kernel<<<gHalfBlk, 256, 0, stream>>>(xf, rowStart, csr_col, dinv, alpha1,
                                                     zf, n, 0);
    gather_half_kernel<<<gHalfBlk, 256, 0, stream>>>(xf, rowStart, csr_col, dinv, alpha1,
                                                     zf, n, 1);

    // ---- fused MFMA: h = relu(z@W1^T+b1); alpha2; yf = h@W2^T ----
    int gblk = (n + 63) / 64;  // 782
    mfma_dense_kernel<<<gblk, 256, 0, stream>>>((const _Float16*)zf, (const _Float16*)w1f,
                                                b1, aw2, ab2, (const _Float16*)w2f,
                                                yfbuf, alpha2, n);

    // ---- layer 2 mix on 40-dim ----
    gather40_kernel<<<(n + 7) / 8, 320, 0, stream>>>(yfbuf, rowStart, csr_col, dinv,
                                                     alpha2, b2, out, n);
}

// Round 14
// 128.734 us; speedup vs baseline: 1.1223x; 1.1223x over previous
//
#include <hip/hip_runtime.h>

#define F 128
#define BIN_CAP 6144   // edges per 256-row bin: mean 3061, sigma ~55 -> 56-sigma margin

typedef _Float16 half8 __attribute__((ext_vector_type(8)));
typedef float f32x4 __attribute__((ext_vector_type(4)));

// ---------- f16 helpers ----------
__device__ inline unsigned int f2_to_h2(float a, float b) {
    union { _Float16 h[2]; unsigned int u; } c;
    c.h[0] = (_Float16)a; c.h[1] = (_Float16)b;
    return c.u;
}
__device__ inline float2 h2_to_f2(unsigned int v) {
    union { unsigned int u; _Float16 h[2]; } c; c.u = v;
    return make_float2((float)c.h[0], (float)c.h[1]);
}

// ---------- row-oriented convert: xf rows + alpha1 (wave/node); tail blocks: W1/W2/binCnt ----------
__global__ __launch_bounds__(256) void convert_kernel(
    const float* __restrict__ x, const float* __restrict__ aw1, const float* __restrict__ ab1,
    const float* __restrict__ W1, const float* __restrict__ W2,
    unsigned int* __restrict__ xf, float* __restrict__ alpha1,
    unsigned int* __restrict__ w1f, unsigned int* __restrict__ w2f,
    int* __restrict__ binCnt, int n, int nodeBlocks) {
    if (blockIdx.x >= nodeBlocks) {
        int i = (blockIdx.x - nodeBlocks) * 256 + threadIdx.x;  // 0..11519
        if (i < 256) {
            binCnt[i] = 0;
        } else if (i < 256 + F * F / 2) {
            int j = i - 256;
            float2 v = ((const float2*)W1)[j];
            w1f[j] = f2_to_h2(v.x, v.y);
        } else {
            int j = i - 256 - F * F / 2;   // [0, 3072)
            int m = j >> 6;
            if (m < 40) {
                float2 v = ((const float2*)W2)[j];
                w2f[j] = f2_to_h2(v.x, v.y);
            } else {
                w2f[j] = 0u;
            }
        }
        return;
    }
    int wid = blockIdx.x * 4 + (threadIdx.x >> 6);
    int lane = threadIdx.x & 63;
    if (wid >= n) return;
    float2 xv = ((const float2*)(x + (size_t)wid * F))[lane];
    float2 awv = ((const float2*)aw1)[lane];
    float s = xv.x * awv.x + xv.y * awv.y;
    #pragma unroll
    for (int off = 32; off > 0; off >>= 1) s += __shfl_down(s, off);
    if (lane == 0) alpha1[wid] = 1.0f / (1.0f + expf(-(s + ab1[0])));
    xf[(size_t)wid * 64 + lane] = f2_to_h2(xv.x, xv.y);
}

// ---------- CSR build via LDS multisplit ----------
__global__ __launch_bounds__(256) void binning_kernel(const int* __restrict__ row,
                                                      const int* __restrict__ col,
                                                      int* __restrict__ binCnt,
                                                      unsigned int* __restrict__ binned, int e) {
    __shared__ int cnt1[256], base[256], cnt2[256];
    int chunk0 = blockIdx.x * 4096;
    cnt1[threadIdx.x] = 0;
    cnt2[threadIdx.x] = 0;
    __syncthreads();
    #pragma unroll
    for (int k = 0; k < 16; ++k) {
        int i = chunk0 + k * 256 + threadIdx.x;
        if (i < e) atomicAdd(&cnt1[row[i] >> 8], 1);
    }
    __syncthreads();
    int c = cnt1[threadIdx.x];
    if (c > 0) base[threadIdx.x] = atomicAdd(&binCnt[threadIdx.x], c);
    __syncthreads();
    #pragma unroll
    for (int k = 0; k < 16; ++k) {
        int i = chunk0 + k * 256 + threadIdx.x;
        if (i < e) {
            int r = row[i], cl = col[i];
            int b = r >> 8;
            int rk = atomicAdd(&cnt2[b], 1);
            int pos = base[b] + rk;
            if (pos < BIN_CAP)  // guard (never triggers at 56 sigma)
                binned[(size_t)b * BIN_CAP + pos] = ((unsigned int)(r & 255) << 24) | (unsigned int)cl;
        }
    }
}

// One block per bin: scan binCnt, LDS-hist 256 rows, write rowStart/dinv/csr_col
__global__ __launch_bounds__(256) void finalize_kernel(const int* __restrict__ binCnt,
                                                       const unsigned int* __restrict__ binned,
                                                       int* __restrict__ rowStart,
                                                       float* __restrict__ dinv,
                                                       int* __restrict__ csr_col,
                                                       int n, int nb) {
    __shared__ int tmp[256], lc[256], lo[256], lc2[256];
    __shared__ int sBase, sSz;
    int tid = threadIdx.x;
    int b = blockIdx.x;
    int v = (tid < nb) ? binCnt[tid] : 0;
    tmp[tid] = v;
    __syncthreads();
    #pragma unroll
    for (int off = 1; off < 256; off <<= 1) {
        int t = (tid >= off) ? tmp[tid - off] : 0;
        __syncthreads();
        tmp[tid] += t;
        __syncthreads();
    }
    if (tid == b) { sBase = tmp[b] - v; sSz = v; }
    lc[tid] = 0;
    lc2[tid] = 0;
    __syncthreads();
    int base = sBase, sz = sSz;
    for (int i = tid; i < sz; i += 256) {
        unsigned int pv = binned[(size_t)b * BIN_CAP + i];
        atomicAdd(&lc[pv >> 24], 1);
    }
    __syncthreads();
    int cv = lc[tid];
    tmp[tid] = cv;
    __syncthreads();
    #pragma unroll
    for (int off = 1; off < 256; off <<= 1) {
        int t = (tid >= off) ? tmp[tid - off] : 0;
        __syncthreads();
        tmp[tid] += t;
        __syncthreads();
    }
    int myLo = tmp[tid] - cv;
    lo[tid] = myLo;
    int rowId = (b << 8) + tid;
    if (rowId < n) {
        rowStart[rowId] = base + myLo;
        dinv[rowId] = rsqrtf((float)(cv + 1));   // +1 self loop
    }
    if (tid == 0 && b == nb - 1) rowStart[n] = base + sz;
    __syncthreads();
    for (int i = tid; i < sz; i += 256) {
        unsigned int pv = binned[(size_t)b * BIN_CAP + i];
        int rl = pv >> 24;
        int rk = atomicAdd(&lc2[rl], 1);
        csr_col[base + lo[rl] + rk] = (int)(pv & 0xFFFFFFu);
    }
}

// ---------- gather: one wave per node, full 256B rows, alpha1 precomputed ----------
__global__ __launch_bounds__(256) void gather_kernel(
    const unsigned int* __restrict__ featf, const int* __restrict__ rowStart,
    const int* __restrict__ csr_col, const float* __restrict__ dinv,
    const float* __restrict__ alpha1, unsigned int* __restrict__ zf, int n) {
    int wid = (blockIdx.x * blockDim.x + threadIdx.x) >> 6;
    int lane = threadIdx.x & 63;
    if (wid >= n) return;
    float2 xv = h2_to_f2(featf[(size_t)wid * 64 + lane]);
    float dr = dinv[wid];
    float2 acc;
    acc.x = dr * dr * xv.x;
    acc.y = dr * dr * xv.y;
    int j = rowStart[wid], en = rowStart[wid + 1];
    for (; j + 3 < en; j += 4) {
        int c0 = csr_col[j], c1 = csr_col[j + 1], c2 = csr_col[j + 2], c3 = csr_col[j + 3];
        float w0 = dr * dinv[c0], w1 = dr * dinv[c1], w2 = dr * dinv[c2], w3 = dr * dinv[c3];
        float2 f0 = h2_to_f2(featf[(size_t)c0 * 64 + lane]);
        float2 f1 = h2_to_f2(featf[(size_t)c1 * 64 + lane]);
        float2 f2 = h2_to_f2(featf[(size_t)c2 * 64 + lane]);
        float2 f3 = h2_to_f2(featf[(size_t)c3 * 64 + lane]);
        acc.x += w0 * f0.x; acc.y += w0 * f0.y;
        acc.x += w1 * f1.x; acc.y += w1 * f1.y;
        acc.x += w2 * f2.x; acc.y += w2 * f2.y;
        acc.x += w3 * f3.x; acc.y += w3 * f3.y;
    }
    for (; j < en; ++j) {
        int c0 = csr_col[j];
        float w0 = dr * dinv[c0];
        float2 f0 = h2_to_f2(featf[(size_t)c0 * 64 + lane]);
        acc.x += w0 * f0.x; acc.y += w0 * f0.y;
    }
    float a = alpha1[wid];
    float ca = 1.0f - a, cb = 2.0f * a - 1.0f;
    zf[(size_t)wid * 64 + lane] = f2_to_h2(ca * xv.x + cb * acc.x, ca * xv.y + cb * acc.y);
}

// ---------- fused dense: h = relu(z@W1^T + b1), alpha2 = sigmoid(h.aw2+ab2), yf = h@W2^T ----------
// 64 nodes/block, 4 waves; wave w owns rows 16w..16w+15.
// MFMA 16x16x32 f16: A lane(l): row=l&15, k=ks*32+(l>>4)*8+j ; B lane(l): col=l&15, same k
// D lane(l): col=l&15, row=(l>>4)*4+r
__global__ __launch_bounds__(256) void mfma_dense_kernel(
    const _Float16* __restrict__ zf, const _Float16* __restrict__ w1f,
    const float* __restrict__ b1, const float* __restrict__ aw2,
    const float* __restrict__ ab2, const _Float16* __restrict__ w2f,
    _Float16* __restrict__ yf, float* __restrict__ alpha2, int n) {
    __shared__ _Float16 hs[64 * F];   // XOR-swizzled: byte ^= (row&7)<<4
    int wv = threadIdx.x >> 6;
    int l = threadIdx.x & 63;
    int lr = l & 15;
    int kg = l >> 4;
    int node0 = blockIdx.x * 64;

    int arow = node0 + wv * 16 + lr;
    bool rowok = arow < n;
    half8 afr[4];
    half8 hzero = {0, 0, 0, 0, 0, 0, 0, 0};
    #pragma unroll
    for (int ks = 0; ks < 4; ++ks) {
        afr[ks] = rowok ? *(const half8*)(zf + (size_t)arow * F + ks * 32 + kg * 8) : hzero;
    }

    f32x4 acc[8];
    #pragma unroll
    for (int ct = 0; ct < 8; ++ct) {
        f32x4 a = {0.f, 0.f, 0.f, 0.f};
        #pragma unroll
        for (int ks = 0; ks < 4; ++ks) {
            half8 b = *(const half8*)(w1f + (size_t)(ct * 16 + lr) * F + ks * 32 + kg * 8);
            a = __builtin_amdgcn_mfma_f32_16x16x32_f16(afr[ks], b, a, 0, 0, 0);
        }
        acc[ct] = a;
    }

    float part[4] = {0.f, 0.f, 0.f, 0.f};
    #pragma unroll
    for (int ct = 0; ct < 8; ++ct) {
        int colc = ct * 16 + lr;
        float bv = b1[colc];
        float av = aw2[colc];
        #pragma unroll
        for (int r = 0; r < 4; ++r) {
            float h = fmaxf(acc[ct][r] + bv, 0.f);
            part[r] += h * av;
            int hrow = wv * 16 + kg * 4 + r;
            int byteoff = (hrow * 256 + colc * 2) ^ ((hrow & 7) << 4);
            *(_Float16*)((char*)hs + byteoff) = (_Float16)h;
        }
    }
    #pragma unroll
    for (int off = 1; off < 16; off <<= 1) {
        #pragma unroll
        for (int r = 0; r < 4; ++r) part[r] += __shfl_xor(part[r], off);
    }
    if (lr == 0) {
        #pragma unroll
        for (int r = 0; r < 4; ++r) {
            int nd = node0 + wv * 16 + kg * 4 + r;
            if (nd < n) alpha2[nd] = 1.0f / (1.0f + expf(-(part[r] + ab2[0])));
        }
    }
    __syncthreads();

    int hrow = wv * 16 + lr;
    half8 a2[4];
    #pragma unroll
    for (int ks = 0; ks < 4; ++ks) {
        int byteoff = (hrow * 256 + (ks * 32 + kg * 8) * 2) ^ ((hrow & 7) << 4);
        a2[ks] = *(const half8*)((char*)hs + byteoff);
    }
    #pragma unroll
    for (int ct = 0; ct < 3; ++ct) {
        f32x4 a = {0.f, 0.f, 0.f, 0.f};
        #pragma unroll
        for (int ks = 0; ks < 4; ++ks) {
            half8 b = *(const half8*)(w2f + (size_t)(ct * 16 + lr) * F + ks * 32 + kg * 8);
            a = __builtin_amdgcn_mfma_f32_16x16x32_f16(a2[ks], b, a, 0, 0, 0);
        }
        int colc = ct * 16 + lr;
        if (colc < 40) {
            #pragma unroll
            for (int r = 0; r < 4; ++r) {
                int nd = node0 + wv * 16 + kg * 4 + r;
                if (nd < n) yf[(size_t)nd * 40 + colc] = (_Float16)a[r];
            }
        }
    }
}

// ---------- gather on 40-dim projected features + mix + bias (final output) ----------
__global__ void gather40_kernel(const _Float16* __restrict__ yf,
                                const int* __restrict__ rowStart, const int* __restrict__ csr_col,
                                const float* __restrict__ dinv, const float* __restrict__ alpha,
                                const float* __restrict__ bias, float* __restrict__ out, int n) {
    int node = blockIdx.x * 8 + threadIdx.x / 40;
    int lane = threadIdx.x % 40;
    if (node >= n) return;
    float yv = (float)yf[(size_t)node * 40 + lane];
    float dr = dinv[node];
    float acc = dr * dr * yv;
    int j = rowStart[node], en = rowStart[node + 1];
    for (; j + 3 < en; j += 4) {
        int c0 = csr_col[j], c1 = csr_col[j + 1], c2 = csr_col[j + 2], c3 = csr_col[j + 3];
        acc += dr * dinv[c0] * (float)yf[(size_t)c0 * 40 + lane];
        acc += dr * dinv[c1] * (float)yf[(size_t)c1 * 40 + lane];
        acc += dr * dinv[c2] * (float)yf[(size_t)c2 * 40 + lane];
        acc += dr * dinv[c3] * (float)yf[(size_t)c3 * 40 + lane];
    }
    for (; j < en; ++j) {
        int c0 = csr_col[j];
        acc += dr * dinv[c0] * (float)yf[(size_t)c0 * 40 + lane];
    }
    float a = alpha[node];
    out[(size_t)node * 40 + lane] = (1.0f - a) * yv + (2.0f * a - 1.0f) * acc + bias[lane];
}

extern "C" void kernel_launch(void* const* d_in, const int* in_sizes, int n_in,
                              void* d_out, int out_size, void* d_ws, size_t ws_size,
                              hipStream_t stream) {
    const float* x   = (const float*)d_in[0];
    const int*   ei  = (const int*)d_in[1];
    const float* aw1 = (const float*)d_in[2];
    const float* ab1 = (const float*)d_in[3];
    const float* W1  = (const float*)d_in[4];
    const float* b1  = (const float*)d_in[5];
    const float* aw2 = (const float*)d_in[6];
    const float* ab2 = (const float*)d_in[7];
    const float* W2  = (const float*)d_in[8];
    const float* b2  = (const float*)d_in[9];
    float* out = (float*)d_out;

    int n = in_sizes[0] / F;   // 50000
    int e = in_sizes[1] / 2;   // 600000
    const int* row = ei;
    const int* col = ei + e;
    int nb = (n + 255) >> 8;   // 196 bins of 256 rows

    // workspace layout, all regions 16B-aligned
    char* p = (char*)d_ws;
    auto alloc = [&](size_t bytes) { char* q = p; p += (bytes + 15) & ~(size_t)15; return q; };
    int*   binCnt   = (int*)alloc(256 * 4);
    int*   rowStart = (int*)alloc((size_t)(n + 2) * 4);
    float* dinv     = (float*)alloc((size_t)n * 4);
    float* alpha1   = (float*)alloc((size_t)n * 4);
    unsigned int* binned = (unsigned int*)alloc((size_t)nb * BIN_CAP * 4);
    int*   csr_col  = (int*)alloc((size_t)e * 4);
    unsigned int* w1f = (unsigned int*)alloc((size_t)F * F * 2);
    unsigned int* w2f = (unsigned int*)alloc((size_t)48 * F * 2);
    unsigned int* xf  = (unsigned int*)alloc((size_t)n * 64 * 4);
    unsigned int* zf  = (unsigned int*)alloc((size_t)n * 64 * 4);
    _Float16* yfbuf = (_Float16*)alloc((size_t)n * 40 * 2);
    float* alpha2   = (float*)alloc((size_t)n * 4);

    // ---- convert (xf rows + alpha1; tail: W1/W2/binCnt) ----
    int nodeBlocks = (n + 3) / 4;                       // 12500
    int tailBlocks = (256 + F * F / 2 + 48 * F / 2 + 255) / 256;  // 45
    convert_kernel<<<nodeBlocks + tailBlocks, 256, 0, stream>>>(
        x, aw1, ab1, W1, W2, xf, alpha1, w1f, w2f, binCnt, n, nodeBlocks);

    // ---- CSR build: multisplit binning + per-bin finalize ----
    binning_kernel<<<(e + 4095) / 4096, 256, 0, stream>>>(row, col, binCnt, binned, e);
    finalize_kernel<<<nb, 256, 0, stream>>>(binCnt, binned, rowStart, dinv, csr_col, n, nb);

    // ---- layer 1 gather -> z (f16), single pass, wave per node ----
    gather_kernel<<<(n + 3) / 4, 256, 0, stream>>>(xf, rowStart, csr_col, dinv, alpha1, zf, n);

    // ---- fused MFMA: h = relu(z@W1^T+b1); alpha2; yf = h@W2^T ----
    int gblk = (n + 63) / 64;  // 782
    mfma_dense_kernel<<<gblk, 256, 0, stream>>>((const _Float16*)zf, (const _Float16*)w1f,
                                                b1, aw2, ab2, (const _Float16*)w2f,
                                                yfbuf, alpha2, n);

    // ---- layer 2 mix on 40-dim ----
    gather40_kernel<<<(n + 7) / 8, 320, 0, stream>>>(yfbuf, rowStart, csr_col, dinv,
                                                     alpha2, b2, out, n);
}